// Round 1
// baseline (141.028 us; speedup 1.0000x reference)
//
#include <hip/hip_runtime.h>

#define Bn 2
#define Nn 4096
#define Cn 256
#define Kn 64

__global__ __launch_bounds__(256) void roi_kernel(
    const float* __restrict__ points,      // (B,N,3)
    const float* __restrict__ feats,       // (B,N,C)
    const float* __restrict__ proposals,   // (B,K,7)
    const float* __restrict__ W1,          // (C,256) row-major
    const float* __restrict__ b1,          // (256)
    const float* __restrict__ W2,          // (256,256)
    const float* __restrict__ b2,          // (256)
    float* __restrict__ out)               // (B,K,256)
{
    const int bk = blockIdx.x;             // 0..B*K-1
    const int b  = bk / Kn;
    const int k  = bk % Kn;
    const int tid = threadIdx.x;           // 0..255

    __shared__ int   s_idx[Nn];            // 16 KiB compact index list
    __shared__ int   s_count;
    __shared__ float s_vec[Cn];            // pooled, then h

    // --- box bounds (strict >lo, <hi; ry ignored, matching reference) ---
    const float* prop = proposals + (size_t)(b * Kn + k) * 7;
    const float cx = prop[0], cy = prop[1], cz = prop[2];
    const float hx = prop[3] * 0.5f, hy = prop[4] * 0.5f, hz = prop[5] * 0.5f;
    const float lox = cx - hx, loy = cy - hy, loz = cz - hz;
    const float hix = cx + hx, hiy = cy + hy, hiz = cz + hz;

    if (tid == 0) s_count = 0;
    __syncthreads();

    // --- phase 1: compact in-box point indices into LDS ---
    const float* pts = points + (size_t)b * Nn * 3;
    for (int n = tid; n < Nn; n += 256) {
        const float px = pts[n * 3 + 0];
        const float py = pts[n * 3 + 1];
        const float pz = pts[n * 3 + 2];
        const bool in = (px > lox) & (px < hix) &
                        (py > loy) & (py < hiy) &
                        (pz > loz) & (pz < hiz);
        if (in) {
            const int pos = atomicAdd(&s_count, 1);
            s_idx[pos] = n;
        }
    }
    __syncthreads();
    const int count = s_count;

    // --- phase 2: per-channel max over selected points (coalesced rows) ---
    float m = -INFINITY;
    const float* fb = feats + (size_t)b * Nn * Cn;
    for (int i = 0; i < count; ++i) {
        const int n = s_idx[i];
        m = fmaxf(m, fb[(size_t)n * Cn + tid]);
    }
    if (count == 0) m = 0.0f;
    s_vec[tid] = m;
    __syncthreads();

    // --- layer 1: h = relu(pooled @ W1 + b1) ---
    float acc = b1[tid];
    #pragma unroll 8
    for (int c = 0; c < Cn; ++c) {
        acc = fmaf(s_vec[c], W1[c * 256 + tid], acc);
    }
    const float h = fmaxf(acc, 0.0f);
    __syncthreads();
    s_vec[tid] = h;
    __syncthreads();

    // --- layer 2: out = relu(h @ W2 + b2) ---
    float acc2 = b2[tid];
    #pragma unroll 8
    for (int c = 0; c < 256; ++c) {
        acc2 = fmaf(s_vec[c], W2[c * 256 + tid], acc2);
    }
    out[(size_t)(b * Kn + k) * 256 + tid] = fmaxf(acc2, 0.0f);
}

extern "C" void kernel_launch(void* const* d_in, const int* in_sizes, int n_in,
                              void* d_out, int out_size, void* d_ws, size_t ws_size,
                              hipStream_t stream) {
    const float* points    = (const float*)d_in[0];
    const float* feats     = (const float*)d_in[1];
    const float* proposals = (const float*)d_in[2];
    const float* W1        = (const float*)d_in[3];
    const float* b1        = (const float*)d_in[4];
    const float* W2        = (const float*)d_in[5];
    const float* b2        = (const float*)d_in[6];
    float* out             = (float*)d_out;

    roi_kernel<<<Bn * Kn, 256, 0, stream>>>(points, feats, proposals, W1, b1, W2, b2, out);
}

// Round 2
// 90.298 us; speedup vs baseline: 1.5618x; 1.5618x over previous
//
#include <hip/hip_runtime.h>

#define Bn 2
#define Nn 4096
#define Cn 256
#define Kn 64
#define BK (Bn * Kn)

// ---------------- Kernel 1: per-segment masked max-pool ----------------
// grid = (B*K, S); block = 256 threads (one per channel).
// ws layout: partial[(bk * S + s) * 256 + c], -inf when segment empty.
__global__ __launch_bounds__(256) void pool_partial_kernel(
    const float* __restrict__ points,      // (B,N,3)
    const float* __restrict__ feats,       // (B,N,C)
    const float* __restrict__ proposals,   // (B,K,7)
    float* __restrict__ partial,           // (B*K, S, 256)
    int S)
{
    const int bk  = blockIdx.x;
    const int s   = blockIdx.y;
    const int b   = bk / Kn;
    const int tid = threadIdx.x;
    const int seg = Nn / S;
    const int n0  = s * seg;

    __shared__ int s_idx[4096];
    __shared__ int s_count;

    const float* prop = proposals + (size_t)bk * 7;
    const float cx = prop[0], cy = prop[1], cz = prop[2];
    const float hx = prop[3] * 0.5f, hy = prop[4] * 0.5f, hz = prop[5] * 0.5f;
    const float lox = cx - hx, loy = cy - hy, loz = cz - hz;
    const float hix = cx + hx, hiy = cy + hy, hiz = cz + hz;

    if (tid == 0) s_count = 0;
    __syncthreads();

    const float* pts = points + (size_t)b * Nn * 3;
    for (int n = n0 + tid; n < n0 + seg; n += 256) {
        const float px = pts[n * 3 + 0];
        const float py = pts[n * 3 + 1];
        const float pz = pts[n * 3 + 2];
        const bool in = (px > lox) & (px < hix) &
                        (py > loy) & (py < hiy) &
                        (pz > loz) & (pz < hiz);
        if (in) {
            const int pos = atomicAdd(&s_count, 1);
            s_idx[pos] = n;
        }
    }
    __syncthreads();
    const int count = s_count;

    const float* fb = feats + (size_t)b * Nn * Cn;
    float m = -INFINITY;
    int i = 0;
    // 8-wide batches: 8 independent LDS index reads -> 8 independent global loads
    for (; i + 8 <= count; i += 8) {
        const int a0 = s_idx[i + 0], a1 = s_idx[i + 1];
        const int a2 = s_idx[i + 2], a3 = s_idx[i + 3];
        const int a4 = s_idx[i + 4], a5 = s_idx[i + 5];
        const int a6 = s_idx[i + 6], a7 = s_idx[i + 7];
        const float f0 = fb[(size_t)a0 * Cn + tid];
        const float f1 = fb[(size_t)a1 * Cn + tid];
        const float f2 = fb[(size_t)a2 * Cn + tid];
        const float f3 = fb[(size_t)a3 * Cn + tid];
        const float f4 = fb[(size_t)a4 * Cn + tid];
        const float f5 = fb[(size_t)a5 * Cn + tid];
        const float f6 = fb[(size_t)a6 * Cn + tid];
        const float f7 = fb[(size_t)a7 * Cn + tid];
        m = fmaxf(m, fmaxf(fmaxf(fmaxf(f0, f1), fmaxf(f2, f3)),
                           fmaxf(fmaxf(f4, f5), fmaxf(f6, f7))));
    }
    for (; i < count; ++i) {
        m = fmaxf(m, fb[(size_t)s_idx[i] * Cn + tid]);
    }

    partial[((size_t)bk * S + s) * Cn + tid] = m;   // -inf if empty
}

// ---------------- Kernel 2: segment reduce + 2-layer MLP ----------------
// grid = B*K blocks; thread d owns output neuron d.
__global__ __launch_bounds__(256) void reduce_mlp_kernel(
    const float* __restrict__ partial,     // (B*K, S, 256)
    const float* __restrict__ W1,          // (C,256)
    const float* __restrict__ b1,
    const float* __restrict__ W2,          // (256,256)
    const float* __restrict__ b2,
    float* __restrict__ out,               // (B,K,256)
    int S)
{
    const int bk  = blockIdx.x;
    const int tid = threadIdx.x;

    __shared__ float s_vec[Cn];

    float m = -INFINITY;
    for (int s = 0; s < S; ++s) {
        m = fmaxf(m, partial[((size_t)bk * S + s) * Cn + tid]);
    }
    if (m == -INFINITY) m = 0.0f;   // empty box -> 0 (matches reference)
    s_vec[tid] = m;
    __syncthreads();

    float acc = b1[tid];
    #pragma unroll 16
    for (int c = 0; c < Cn; ++c) {
        acc = fmaf(s_vec[c], W1[c * 256 + tid], acc);
    }
    const float h = fmaxf(acc, 0.0f);
    __syncthreads();
    s_vec[tid] = h;
    __syncthreads();

    float acc2 = b2[tid];
    #pragma unroll 16
    for (int c = 0; c < 256; ++c) {
        acc2 = fmaf(s_vec[c], W2[c * 256 + tid], acc2);
    }
    out[(size_t)bk * 256 + tid] = fmaxf(acc2, 0.0f);
}

extern "C" void kernel_launch(void* const* d_in, const int* in_sizes, int n_in,
                              void* d_out, int out_size, void* d_ws, size_t ws_size,
                              hipStream_t stream) {
    const float* points    = (const float*)d_in[0];
    const float* feats     = (const float*)d_in[1];
    const float* proposals = (const float*)d_in[2];
    const float* W1        = (const float*)d_in[3];
    const float* b1        = (const float*)d_in[4];
    const float* W2        = (const float*)d_in[5];
    const float* b2        = (const float*)d_in[6];
    float* out             = (float*)d_out;
    float* partial         = (float*)d_ws;

    // pick largest segment count S (power of 2) fitting in the workspace
    int S = 8;
    while (S > 1 && (size_t)BK * S * Cn * sizeof(float) > ws_size) S >>= 1;

    dim3 grid1(BK, S);
    pool_partial_kernel<<<grid1, 256, 0, stream>>>(points, feats, proposals, partial, S);
    reduce_mlp_kernel<<<BK, 256, 0, stream>>>(partial, W1, b1, W2, b2, out, S);
}